// Round 13
// baseline (297.177 us; speedup 1.0000x reference)
//
#include <hip/hip_runtime.h>
#include <hip/hip_bf16.h>

// Problem constants (match reference)
constexpr int cN = 50000;
constexpr int cE = 800000;
constexpr int cNUM_CLASSES = 40;
constexpr int cFEAT_DIM = 256;
constexpr int cFEAT_HID = 64;
constexpr int cDEG_HID = 32;
constexpr int cHID = 128;
constexpr int cMAX_DEG = 256;
constexpr int cKF = 352;                // fused conv1 K: 40 logits + 256 feat + 32 deg + 24 pad
constexpr int cLSTR = 40;               // LDS row stride (shorts): 80 B -> 2-way (free) bank aliasing

// LDS-histogram CSR build parameters (cNCHUNK=128: measured-safe absmax ordering)
constexpr int cNCHUNK = 128;            // edge chunks (= copies per histogram)
constexpr int cCHUNK  = cE / cNCHUNK;   // 6250 edges per chunk (exact)
constexpr int cWORDS  = cN / 2;         // 25000 packed u16-pair words per histogram
constexpr int cHWORDS = cWORDS / 2;     // 12500 words per node-range half (50 KB LDS)
constexpr int cSCANB  = (cWORDS + 255) / 256; // 98 blocks for mega_scan

typedef unsigned short ushort8_t __attribute__((ext_vector_type(8)));
typedef short short8_t __attribute__((ext_vector_type(8)));
typedef float float4_t __attribute__((ext_vector_type(4)));

__device__ __forceinline__ unsigned short f2bf(float f) {
    unsigned u = __builtin_bit_cast(unsigned, f);
    u += 0x7fff + ((u >> 16) & 1); // RNE
    return (unsigned short)(u >> 16);
}
__device__ __forceinline__ float bf2f(unsigned short s) {
    unsigned u = ((unsigned)s) << 16;
    return __builtin_bit_cast(float, u);
}

// ---------------- prep: histograms + all weight preprocessing + desc init ----------------
// blocks 0..511:   LDS histograms -> partial[which][chunk][word] (cb=b&127, half=(b>>7)&1, which=b>>8)
// blocks 512..647: Btc W1-part (k<40, 296..351) + Wt2 + Wt3
// blocks 648..775: Wc = Wf@W1[40:104] -> Btc k 40..295
// block 776:       bias2 = bf@W1[40:104] ; desc[0..97] = 0
__global__ __launch_bounds__(256) void prep_kernel(const int* __restrict__ edge,
                                                   unsigned* __restrict__ partial,
                                                   const float* __restrict__ Wf,
                                                   const float* __restrict__ bfv,
                                                   const float* __restrict__ W1,
                                                   const float* __restrict__ W2,
                                                   const float* __restrict__ W3,
                                                   unsigned short* __restrict__ Btc,
                                                   unsigned short* __restrict__ Wt2,
                                                   unsigned short* __restrict__ Wt3,
                                                   float* __restrict__ bias2,
                                                   int* __restrict__ desc) {
    __shared__ unsigned lds[cHWORDS];
    const int b = blockIdx.x, tid = threadIdx.x;
    if (b < 512) {
        const int cb = b & (cNCHUNK - 1);
        const int half = (b >> 7) & 1;
        const int which = b >> 8;
        for (int i = tid; i < cHWORDS; i += 256) lds[i] = 0;
        __syncthreads();
        const int* ids = edge + (size_t)which * cE + (size_t)cb * cCHUNK;
        const int lo = half * (cN / 2), hi = lo + cN / 2;
        const int wbase = half * cHWORDS;
        for (int i = tid; i < cCHUNK; i += 256) {
            int v = ids[i];
            if (v >= lo && v < hi)
                atomicAdd(&lds[(v >> 1) - wbase], 1u << ((v & 1) * 16));
        }
        __syncthreads();
        unsigned* outp = partial + ((size_t)which * cNCHUNK + cb) * cWORDS + wbase;
        for (int i = tid; i < cHWORDS; i += 256) outp[i] = lds[i];
        return;
    }
    if (b < 648) {
        int i = (b - 512) * 256 + tid;
        if (i < 12288) {            // Btc: logits rows, deg rows, zero pad
            int n = i / 96, r = i - (i / 96) * 96;
            unsigned short v;
            if (r < 40)       v = f2bf(W1[r * cHID + n]);
            else if (r < 72)  v = f2bf(W1[(104 + r - 40) * cHID + n]);
            else              v = 0;
            int k = (r < 40) ? r : (r < 72 ? 296 + (r - 40) : 328 + (r - 72));
            Btc[n * cKF + k] = v;
            return;
        }
        i -= 12288;
        if (i < 16384) {            // Wt2
            int n = i >> 7, k = i & 127;
            Wt2[n * cHID + k] = f2bf(W2[k * cHID + n]);
            return;
        }
        i -= 16384;
        if (i < 6144) {             // Wt3 (48 x 128, n>=40 zero)
            int n = i >> 7, k = i & 127;
            Wt3[n * cHID + k] = (n < cNUM_CLASSES) ? f2bf(W3[k * cNUM_CLASSES + n]) : 0;
        }
        return;
    }
    if (b < 776) {                  // Wc[kf][n] = sum_j Wf[kf][j] * W1[40+j][n]
        int i = (b - 648) * 256 + tid;
        int kf = i >> 7, n = i & 127;
        float s = 0.f;
        #pragma unroll 8
        for (int j = 0; j < cFEAT_HID; ++j)
            s += Wf[kf * cFEAT_HID + j] * W1[(40 + j) * cHID + n];
        Btc[n * cKF + 40 + kf] = f2bf(s);
        return;
    }
    // bias2 + desc init
    if (tid < cHID) {
        float s = 0.f;
        #pragma unroll 8
        for (int j = 0; j < cFEAT_HID; ++j)
            s += bfv[j] * W1[(40 + j) * cHID + tid];
        bias2[tid] = s;
    } else if (tid - 128 < cSCANB) {
        desc[tid - 128] = 0;
    }
}

// ---------------- mega_scan: merge copies, chunk-prefix rewrite, rowptr, dinv, degidx ----------------
__global__ __launch_bounds__(256) void mega_scan_kernel(unsigned* __restrict__ partial,
                                                        int* __restrict__ rowptr,
                                                        float* __restrict__ dinv,
                                                        int* __restrict__ degidx,
                                                        int* __restrict__ desc) {
    const int b = blockIdx.x, tid = threadIdx.x;
    const int w = b * 256 + tid;
    unsigned slo = 0, shi = 0, plo = 0, phi = 0;
    if (w < cWORDS) {
        const unsigned* ps = partial + w;
        for (int c = 0; c < cNCHUNK; ++c) {
            unsigned v = ps[(size_t)c * cWORDS];
            slo += v & 0xFFFFu; shi += v >> 16;
        }
        unsigned* pd = partial + (size_t)cNCHUNK * cWORDS + w;
        for (int c = 0; c < cNCHUNK; ++c) {
            unsigned v = pd[(size_t)c * cWORDS];
            pd[(size_t)c * cWORDS] = plo | (phi << 16);   // per-chunk prefix (fits u16)
            plo += v & 0xFFFFu; phi += v >> 16;
        }
        int d0 = (int)(slo + plo), d1 = (int)(shi + phi);
        degidx[2 * w]     = d0 > cMAX_DEG - 1 ? cMAX_DEG - 1 : d0;
        degidx[2 * w + 1] = d1 > cMAX_DEG - 1 ? cMAX_DEG - 1 : d1;
    }
    __shared__ int s[256];
    int tot = (int)(plo + phi);
    s[tid] = tot;
    __syncthreads();
    #pragma unroll
    for (int off = 1; off < 256; off <<= 1) {
        int t = (tid >= off) ? s[tid - off] : 0;
        __syncthreads();
        s[tid] += t;
        __syncthreads();
    }
    int ex_local = s[tid] - tot;
    int block_total = s[255];
    if (tid == 0) atomicExch(&desc[b], block_total + 1);
    if (tid < b) {
        int v;
        do { v = atomicAdd(&desc[tid], 0); } while (v == 0);
        s[tid] = v - 1;
    }
    __syncthreads();
    if (tid >= b) s[tid] = 0;
    __syncthreads();
    #pragma unroll
    for (int off = 128; off > 0; off >>= 1) {
        if (tid < off) s[tid] += s[tid + off];
        __syncthreads();
    }
    int base = s[0] + ex_local;
    if (w < cWORDS) {
        rowptr[2 * w]     = base;
        rowptr[2 * w + 1] = base + (int)plo;
        dinv[2 * w]     = rsqrtf((float)(plo + 1));
        dinv[2 * w + 1] = rsqrtf((float)(phi + 1));
    }
    if (b == 0 && tid == 0) rowptr[cN] = cE;
}

// ---------------- deterministic scatter (no global atomics) ----------------
__global__ __launch_bounds__(256) void scatter2_kernel(const int* __restrict__ edge,
                                                       const unsigned* __restrict__ partial,
                                                       const int* __restrict__ rowptr,
                                                       int* __restrict__ adj) {
    __shared__ unsigned lds[cHWORDS];
    const int b = blockIdx.x, tid = threadIdx.x;
    const int cb = b & (cNCHUNK - 1);
    const int half = b >> 7;
    const int wbase = half * cHWORDS;
    const unsigned* pp = partial + ((size_t)cNCHUNK + cb) * cWORDS + wbase;
    for (int i = tid; i < cHWORDS; i += 256) lds[i] = pp[i];
    __syncthreads();
    const int* srcs = edge + (size_t)cb * cCHUNK;
    const int* dsts = edge + cE + (size_t)cb * cCHUNK;
    const int lo = half * (cN / 2), hi = lo + cN / 2;
    for (int i = tid; i < cCHUNK; i += 256) {
        int d = dsts[i];
        if (d >= lo && d < hi) {
            int sh = (d & 1) * 16;
            unsigned old = atomicAdd(&lds[(d >> 1) - wbase], 1u << sh);
            int off = (int)((old >> sh) & 0xFFFFu);
            adj[rowptr[d] + off] = srcs[i];
        }
    }
}

// ---------------- fused conv1 GEMM: t = [logits|features|deg_emb] @ Btc^T + bias2 ----------------
__global__ __launch_bounds__(256) void gemm_fused(const float* __restrict__ logits,
                                                  const float* __restrict__ features,
                                                  const float* __restrict__ deg_table,
                                                  const int* __restrict__ degidx,
                                                  const unsigned short* __restrict__ Btc,
                                                  const float* __restrict__ bias2,
                                                  unsigned short* __restrict__ out) {
    constexpr int NT = 8;
    __shared__ unsigned short As[64 * cLSTR];
    __shared__ unsigned short Bs[NT * 16 * cLSTR];

    const int tid = threadIdx.x;
    const int wave = tid >> 6;
    const int lane = tid & 63;
    const int m15 = lane & 15;
    const int q = lane >> 4;
    const int rowbase = blockIdx.x * 64;

    float4_t acc[NT];
    #pragma unroll
    for (int t = 0; t < NT; ++t) acc[t] = (float4_t){0.f, 0.f, 0.f, 0.f};

    const int arow = tid >> 2;
    const int akq = (tid & 3) * 8;
    int gr = rowbase + arow;
    if (gr > cN - 1) gr = cN - 1;
    const int didx = degidx[gr];

    for (int k0 = 0; k0 < cKF; k0 += 32) {
        float4 v[2];
        #pragma unroll
        for (int h = 0; h < 2; ++h) {
            int k4 = k0 + akq + h * 4;
            v[h] = make_float4(0.f, 0.f, 0.f, 0.f);
            if (k4 < 40)       v[h] = *(const float4*)&logits[(size_t)gr * cNUM_CLASSES + k4];
            else if (k4 < 296) v[h] = *(const float4*)&features[(size_t)gr * cFEAT_DIM + (k4 - 40)];
            else if (k4 < 328) v[h] = *(const float4*)&deg_table[didx * cDEG_HID + (k4 - 296)];
        }
        ushort8_t o = { f2bf(v[0].x), f2bf(v[0].y), f2bf(v[0].z), f2bf(v[0].w),
                        f2bf(v[1].x), f2bf(v[1].y), f2bf(v[1].z), f2bf(v[1].w) };
        *(ushort8_t*)&As[arow * cLSTR + akq] = o;
        for (int i = tid; i < NT * 64; i += 256) {
            int n = i >> 2;
            int kq = (i & 3) * 8;
            *(ushort8_t*)&Bs[n * cLSTR + kq] = *(const ushort8_t*)&Btc[(size_t)n * cKF + k0 + kq];
        }
        __syncthreads();

        short8_t a = *(const short8_t*)&As[(wave * 16 + m15) * cLSTR + q * 8];
        #pragma unroll
        for (int t = 0; t < NT; ++t) {
            short8_t bfr = *(const short8_t*)&Bs[(t * 16 + m15) * cLSTR + q * 8];
            acc[t] = __builtin_amdgcn_mfma_f32_16x16x32_bf16(a, bfr, acc[t], 0, 0, 0);
        }
        __syncthreads();
    }

    #pragma unroll
    for (int t = 0; t < NT; ++t) {
        int col = t * 16 + m15;
        float bv = bias2[col];
        #pragma unroll
        for (int r = 0; r < 4; ++r) {
            int row = rowbase + wave * 16 + q * 4 + r;
            if (row < cN)
                out[(size_t)row * cHID + col] = f2bf(acc[t][r] + bv);
        }
    }
}

// ---------------- MFMA GEMM (bf16 A): out[m][n] = A@Bt^T, bf16 out ----------------
template <int KTOT, int NT, int OSTR, int OUTC>
__global__ __launch_bounds__(256) void mfma_gemm(const unsigned short* __restrict__ A,
                                                 const unsigned short* __restrict__ Bt,
                                                 unsigned short* __restrict__ out) {
    __shared__ unsigned short As[64 * cLSTR];
    __shared__ unsigned short Bs[NT * 16 * cLSTR];

    const int tid = threadIdx.x;
    const int wave = tid >> 6;
    const int lane = tid & 63;
    const int m15 = lane & 15;
    const int q = lane >> 4;
    const int rowbase = blockIdx.x * 64;

    float4_t acc[NT];
    #pragma unroll
    for (int t = 0; t < NT; ++t) acc[t] = (float4_t){0.f, 0.f, 0.f, 0.f};

    const int arow = tid >> 2;
    const int akq = (tid & 3) * 8;
    int gr = rowbase + arow;
    if (gr > cN - 1) gr = cN - 1;

    for (int k0 = 0; k0 < KTOT; k0 += 32) {
        *(ushort8_t*)&As[arow * cLSTR + akq] =
            *(const ushort8_t*)&A[(size_t)gr * KTOT + k0 + akq];
        for (int i = tid; i < NT * 64; i += 256) {
            int n = i >> 2;
            int kq = (i & 3) * 8;
            *(ushort8_t*)&Bs[n * cLSTR + kq] = *(const ushort8_t*)&Bt[(size_t)n * KTOT + k0 + kq];
        }
        __syncthreads();

        short8_t a = *(const short8_t*)&As[(wave * 16 + m15) * cLSTR + q * 8];
        #pragma unroll
        for (int t = 0; t < NT; ++t) {
            short8_t b = *(const short8_t*)&Bs[(t * 16 + m15) * cLSTR + q * 8];
            acc[t] = __builtin_amdgcn_mfma_f32_16x16x32_bf16(a, b, acc[t], 0, 0, 0);
        }
        __syncthreads();
    }

    #pragma unroll
    for (int t = 0; t < NT; ++t) {
        int col = t * 16 + m15;
        if (OUTC % 16 != 0 && col >= OUTC) continue;
        #pragma unroll
        for (int r = 0; r < 4; ++r) {
            int row = rowbase + wave * 16 + q * 4 + r;
            if (row < cN)
                out[(size_t)row * OSTR + col] = f2bf(acc[t][r]);
        }
    }
}

// ---------------- GCN aggregate over bf16 t, 128 channels -> bf16 out (R8 best config) ----------------
template <bool RELU>
__global__ __launch_bounds__(128) void agg_bf128(const unsigned short* __restrict__ t,
                                                 const int* __restrict__ rowptr,
                                                 const int* __restrict__ adj,
                                                 const float* __restrict__ dinv,
                                                 const float* __restrict__ b,
                                                 unsigned short* __restrict__ outb) {
    const int tid = threadIdx.x;
    const int lane = tid & 15;
    const int row = blockIdx.x * 8 + (tid >> 4);
    if (row >= cN) return;
    const int c = lane * 8;
    const float di = dinv[row];
    int e = rowptr[row];
    const int end = rowptr[row + 1];
    float a0[8], a1[8];
    #pragma unroll
    for (int k = 0; k < 8; ++k) { a0[k] = 0.f; a1[k] = 0.f; }
    for (; e + 1 < end; e += 2) {
        int j0 = adj[e], j1 = adj[e + 1];
        float v0 = dinv[j0], v1 = dinv[j1];
        ushort8_t t0 = *(const ushort8_t*)&t[(size_t)j0 * cHID + c];
        ushort8_t t1 = *(const ushort8_t*)&t[(size_t)j1 * cHID + c];
        #pragma unroll
        for (int k = 0; k < 8; ++k) {
            a0[k] += v0 * bf2f(t0[k]);
            a1[k] += v1 * bf2f(t1[k]);
        }
    }
    if (e < end) {
        int j0 = adj[e];
        float v0 = dinv[j0];
        ushort8_t t0 = *(const ushort8_t*)&t[(size_t)j0 * cHID + c];
        #pragma unroll
        for (int k = 0; k < 8; ++k) a0[k] += v0 * bf2f(t0[k]);
    }
    ushort8_t ts = *(const ushort8_t*)&t[(size_t)row * cHID + c];
    const float d2 = di * di;
    ushort8_t o;
    #pragma unroll
    for (int k = 0; k < 8; ++k) {
        float r = di * (a0[k] + a1[k]) + d2 * bf2f(ts[k]) + b[c + k];
        if (RELU) r = fmaxf(r, 0.f);
        o[k] = f2bf(r);
    }
    *(ushort8_t*)&outb[(size_t)row * cHID + c] = o;
}

// ---------------- GCN aggregate over bf16 t, 40 channels (final, fp32 out; R8 config) ----------------
__global__ __launch_bounds__(128) void agg_bf40(const unsigned short* __restrict__ t,
                                                const int* __restrict__ rowptr,
                                                const int* __restrict__ adj,
                                                const float* __restrict__ dinv,
                                                const float* __restrict__ b,
                                                float* __restrict__ out) {
    const int tid = threadIdx.x;
    const int lane = tid & 7;
    const int row = blockIdx.x * 16 + (tid >> 3);
    if (row >= cN) return;
    const int c = lane * 8;
    if (c >= cNUM_CLASSES) return;
    const float di = dinv[row];
    int e = rowptr[row];
    const int end = rowptr[row + 1];
    float a0[8], a1[8];
    #pragma unroll
    for (int k = 0; k < 8; ++k) { a0[k] = 0.f; a1[k] = 0.f; }
    for (; e + 1 < end; e += 2) {
        int j0 = adj[e], j1 = adj[e + 1];
        float v0 = dinv[j0], v1 = dinv[j1];
        ushort8_t t0 = *(const ushort8_t*)&t[(size_t)j0 * cNUM_CLASSES + c];
        ushort8_t t1 = *(const ushort8_t*)&t[(size_t)j1 * cNUM_CLASSES + c];
        #pragma unroll
        for (int k = 0; k < 8; ++k) {
            a0[k] += v0 * bf2f(t0[k]);
            a1[k] += v1 * bf2f(t1[k]);
        }
    }
    if (e < end) {
        int j0 = adj[e];
        float v0 = dinv[j0];
        ushort8_t t0 = *(const ushort8_t*)&t[(size_t)j0 * cNUM_CLASSES + c];
        #pragma unroll
        for (int k = 0; k < 8; ++k) a0[k] += v0 * bf2f(t0[k]);
    }
    ushort8_t ts = *(const ushort8_t*)&t[(size_t)row * cNUM_CLASSES + c];
    const float d2 = di * di;
    float r[8];
    #pragma unroll
    for (int k = 0; k < 8; ++k) r[k] = di * (a0[k] + a1[k]) + d2 * bf2f(ts[k]) + b[c + k];
    float4 v0 = make_float4(r[0], r[1], r[2], r[3]);
    float4 v1 = make_float4(r[4], r[5], r[6], r[7]);
    *(float4*)&out[(size_t)row * cNUM_CLASSES + c] = v0;
    *(float4*)&out[(size_t)row * cNUM_CLASSES + c + 4] = v1;
}

extern "C" void kernel_launch(void* const* d_in, const int* in_sizes, int n_in,
                              void* d_out, int out_size, void* d_ws, size_t ws_size,
                              hipStream_t stream) {
    const float* logits    = (const float*)d_in[0];
    const float* features  = (const float*)d_in[1];
    const int*   edge      = (const int*)d_in[2];
    const float* Wf        = (const float*)d_in[3];
    const float* bfv       = (const float*)d_in[4];
    const float* deg_table = (const float*)d_in[5];
    const float* W1        = (const float*)d_in[6];
    const float* b1        = (const float*)d_in[7];
    const float* W2        = (const float*)d_in[8];
    const float* b2        = (const float*)d_in[9];
    const float* W3        = (const float*)d_in[10];
    const float* b3        = (const float*)d_in[11];
    float* out = (float*)d_out;

    // workspace carve-up (16B-aligned sections)
    int* rowptr    = (int*)d_ws;                 // N+1 (padded)
    int* adj       = rowptr + cN + 16;           // E
    int* desc      = adj + cE;                   // 128
    int* degidx    = desc + 128;                 // N
    float* dinv    = (float*)(degidx + cN);      // N
    float* bias2   = dinv + cN;                  // 128
    unsigned short* tb  = (unsigned short*)(bias2 + 128);          // N*128 bf16
    unsigned short* hb  = tb + (size_t)cN * cHID;                  // N*128 bf16
    unsigned short* Btc = hb + (size_t)cN * cHID;                  // 128*352
    unsigned short* Wt2 = Btc + 128 * cKF;                         // 128*128
    unsigned short* Wt3 = Wt2 + 128 * cHID;                        // 48*128
    unsigned* partial = (unsigned*)(Wt3 + 48 * cHID);              // 2*128*25000 u32

    // histograms + all weight preprocessing + desc init (one launch, 777 blocks)
    prep_kernel<<<777, 256, 0, stream>>>(edge, partial, Wf, bfv, W1, W2, W3,
                                         Btc, Wt2, Wt3, bias2, desc);

    // merged scan: chunk-prefix rewrite, rowptr, dinv, degidx (one launch, parallel lookback)
    mega_scan_kernel<<<cSCANB, 256, 0, stream>>>(partial, rowptr, dinv, degidx, desc);

    // CSR scatter (no global atomics)
    scatter2_kernel<<<256, 256, 0, stream>>>(edge, partial, rowptr, adj);

    constexpr int MB = (cN + 63) / 64; // 782

    // conv1 (fused frontend): tb = bf16([logits|feat|deg_emb] @ Btc^T + bias2)
    gemm_fused<<<MB, 256, 0, stream>>>(logits, features, deg_table, degidx, Btc, bias2, tb);
    agg_bf128<true><<<(cN + 7) / 8, 128, 0, stream>>>(tb, rowptr, adj, dinv, b1, hb);

    // conv2
    mfma_gemm<cHID, 8, cHID, cHID><<<MB, 256, 0, stream>>>(hb, Wt2, tb);
    agg_bf128<true><<<(cN + 7) / 8, 128, 0, stream>>>(tb, rowptr, adj, dinv, b2, hb);

    // conv3
    mfma_gemm<cHID, 3, cNUM_CLASSES, cNUM_CLASSES><<<MB, 256, 0, stream>>>(hb, Wt3, tb);
    agg_bf40<<<(cN + 15) / 16, 128, 0, stream>>>(tb, rowptr, adj, dinv, b3, out);
}